// Round 12
// baseline (500.979 us; speedup 1.0000x reference)
//
#include <hip/hip_runtime.h>
#include <hip/hip_bf16.h>

#define NPIX 196608
#define CIN  32
#define COUT 64
#define KNB  9
#define BATCH 4

typedef short short8 __attribute__((ext_vector_type(8)));
typedef float f32x4  __attribute__((ext_vector_type(4)));
typedef unsigned int uint4v __attribute__((ext_vector_type(4)));

static __device__ __forceinline__ unsigned short f2bf(float f) {
    union { float f; unsigned int u; } v; v.f = f;
    unsigned int r = v.u + 0x7FFFu + ((v.u >> 16) & 1u);   // RNE
    return (unsigned short)(r >> 16);
}

// ---------------------------------------------------------------------------
// Kernel 1: pack W (COUT,CIN,K) fp32 -> bf16 in MFMA A-fragment order.
// Wp[((k*4+m)*64 + lane)*8 + j] = bf16( W[o=m*16+(lane&15)][c=(lane>>4)*8+j][k] )
// ---------------------------------------------------------------------------
__global__ __launch_bounds__(256) void wpack_kernel(const float* __restrict__ W,
                                                    unsigned short* __restrict__ Wp) {
    int e = blockIdx.x * 256 + threadIdx.x;
    if (e >= 18432) return;
    int j = e & 7;
    int l = (e >> 3) & 63;
    int m = (e >> 9) & 3;
    int k = e >> 11;                       // 0..8
    int o = m * 16 + (l & 15);
    int c = ((l >> 4) << 3) + j;
    Wp[e] = f2bf(W[(o * CIN + c) * KNB + k]);
}

// ---------------------------------------------------------------------------
// Kernel 2: transpose+convert x (B,CIN,NPIX) fp32 -> xT pixel-major:
// xT[p][b][c] bf16 — 256 B per pixel. float4 NT loads (single-use x),
// LDS [64][68], REGULAR xT stores (keep xT warm in L2/L3 for conv's
// first-touch gathers — r11 had NT here, pushing xT toward HBM).
// ---------------------------------------------------------------------------
__global__ __launch_bounds__(256) void xpose_kernel(const float* __restrict__ x,
                                                    unsigned short* __restrict__ xT) {
    __shared__ unsigned int lds[64][68];
    int t  = threadIdx.x;
    int p0 = blockIdx.x * 64;                // 3072 blocks
    int c2 = t >> 4;                         // channel pair 0..15
    int pg = (t & 15) * 4;                   // pixel group of 4

    #pragma unroll
    for (int b = 0; b < 4; ++b) {
        const float* xr = x + ((size_t)(b * CIN + 2 * c2)) * NPIX + p0 + pg;
        f32x4 lo = __builtin_nontemporal_load((const f32x4*)xr);
        f32x4 hi = __builtin_nontemporal_load((const f32x4*)(xr + NPIX));
        #pragma unroll
        for (int j = 0; j < 4; ++j)
            lds[pg + j][b * 16 + c2] =
                (unsigned int)f2bf(lo[j]) | ((unsigned int)f2bf(hi[j]) << 16);
    }
    __syncthreads();
    unsigned int* dst = (unsigned int*)xT + (size_t)p0 * 64;
    #pragma unroll
    for (int i = 0; i < 4; ++i) {
        int ub = (i * 256 + t) * 4;          // uint index, 16B-aligned
        uint4v v = *(const uint4v*)&lds[ub >> 6][ub & 63];
        *(uint4v*)(dst + ub) = v;            // regular store (L2-resident)
    }
}

// ---------------------------------------------------------------------------
// Kernel 3: main gather + MFMA GEMM, batch-fused.
// Block = 64 pixels x ALL 4 batches; wave w handles batch w.
// __launch_bounds__(256,8): 8 blocks/CU (LDS 19.97KB x 8 = 159.7KB fits,
// VGPR 56 <= 64) — isolated occupancy test: doubles in-flight gathers.
// unroll 3 (r9: unroll-9 regressed). Epilogue: wave-private LDS transpose
// -> full-line NT stores, no barriers.
// ---------------------------------------------------------------------------
template <bool TR>
__global__ __launch_bounds__(256, 8) void conv_kernel(const unsigned short* __restrict__ xT,
                                                      const float* __restrict__ x,
                                                      const int* __restrict__ nbr,
                                                      const unsigned short* __restrict__ Wp,
                                                      const float* __restrict__ bias,
                                                      float* __restrict__ out) {
    __shared__ int   ilds[576];              // 64 px * 9 nbrs
    __shared__ float elds[4][16][68];        // per-wave transpose tile, 17.4 KB

    int t  = threadIdx.x;
    int p0 = blockIdx.x * 64;                // 3072 blocks

    for (int i = t; i < 576; i += 256) {
        int idx = __builtin_nontemporal_load(&nbr[p0 * KNB + i]);
        ilds[i] = TR ? (idx << 8) : idx;     // *256B pixel block
    }
    __syncthreads();

    int lane = t & 63;
    int w    = t >> 6;                       // wave = batch
    int r    = lane & 15;
    int q    = lane >> 4;

    f32x4 acc[4][4] = {};                    // [m-tile][px-frag]

    const char* xb = (const char*)xT + w * 64 + q * 16;
    const unsigned short* wl = Wp + (size_t)lane * 8;

    int prow[4];
    #pragma unroll
    for (int f = 0; f < 4; ++f) prow[f] = (f * 16 + r) * KNB;

    #pragma unroll 3
    for (int k = 0; k < KNB; ++k) {
        short8 bfrag[4];
        #pragma unroll
        for (int f = 0; f < 4; ++f) {
            int off = ilds[prow[f] + k];
            if (TR) {
                bfrag[f] = *(const short8*)(xb + off);
            } else {
                const float* xc = x + (size_t)(w * CIN + q * 8) * NPIX + off;
                #pragma unroll
                for (int j = 0; j < 8; ++j)
                    bfrag[f][j] = (short)f2bf(xc[(size_t)j * NPIX]);
            }
        }
        short8 afr[4];
        #pragma unroll
        for (int m = 0; m < 4; ++m)
            afr[m] = *(const short8*)(wl + (((k << 2) | m) << 9));   // ((k*4+m)*64)*8
        #pragma unroll
        for (int m = 0; m < 4; ++m)
            #pragma unroll
            for (int f = 0; f < 4; ++f)
                acc[m][f] = __builtin_amdgcn_mfma_f32_16x16x32_bf16(
                                afr[m], bfrag[f], acc[m][f], 0, 0, 0);
    }

    // epilogue: per m-tile, transpose through wave-private LDS -> full-line
    // NT stores. acc[m][f][rr] = (cout_local = q*4+rr, px = f*16+r)
    float* ob = out + (size_t)w * COUT * NPIX + p0;
    #pragma unroll
    for (int m = 0; m < 4; ++m) {
        f32x4 bv = *(const f32x4*)(bias + m * 16 + q * 4);
        #pragma unroll
        for (int f = 0; f < 4; ++f)
            #pragma unroll
            for (int rr = 0; rr < 4; ++rr)
                elds[w][q * 4 + rr][f * 16 + r] = acc[m][f][rr] + bv[rr];
        #pragma unroll
        for (int i = 0; i < 4; ++i) {
            int g   = i * 64 + lane;         // 0..255 per wave
            int row = g >> 4;                // 0..15
            int col = (g & 15) * 4;          // 0..60
            f32x4 v = *(const f32x4*)&elds[w][row][col];
            __builtin_nontemporal_store(v,
                (f32x4*)(ob + (size_t)(m * 16 + row) * NPIX + col));
        }
    }
}

// ---------------------------------------------------------------------------
extern "C" void kernel_launch(void* const* d_in, const int* in_sizes, int n_in,
                              void* d_out, int out_size, void* d_ws, size_t ws_size,
                              hipStream_t stream) {
    const float* x    = (const float*)d_in[0];
    const int*   nbr  = (const int*)d_in[1];
    const float* W    = (const float*)d_in[2];
    const float* bias = (const float*)d_in[3];
    float*       out  = (float*)d_out;

    const size_t wp_bytes = 18432 * sizeof(unsigned short);           // 36,864
    const size_t wp_pad   = (wp_bytes + 255) & ~(size_t)255;
    const size_t xT_bytes = (size_t)BATCH * NPIX * CIN * 2;           // ~50.3 MB

    unsigned short* Wp = (unsigned short*)d_ws;
    unsigned short* xT = (unsigned short*)((char*)d_ws + wp_pad);

    bool full = ws_size >= wp_pad + xT_bytes;

    wpack_kernel<<<72, 256, 0, stream>>>(W, Wp);
    if (full) {
        xpose_kernel<<<NPIX / 64, 256, 0, stream>>>(x, xT);
        conv_kernel<true><<<NPIX / 64, 256, 0, stream>>>(xT, x, nbr, Wp, bias, out);
    } else {
        conv_kernel<false><<<NPIX / 64, 256, 0, stream>>>(xT, x, nbr, Wp, bias, out);
    }
}

// Round 14
// 136.591 us; speedup vs baseline: 3.6677x; 3.6677x over previous
//
#include <hip/hip_runtime.h>
#include <hip/hip_bf16.h>

#define NPIX 196608
#define CIN  32
#define COUT 64
#define KNB  9
#define BATCH 4

typedef short short8 __attribute__((ext_vector_type(8)));
typedef float f32x4  __attribute__((ext_vector_type(4)));
typedef unsigned int uint4v __attribute__((ext_vector_type(4)));

static __device__ __forceinline__ unsigned short f2bf(float f) {
    union { float f; unsigned int u; } v; v.f = f;
    unsigned int r = v.u + 0x7FFFu + ((v.u >> 16) & 1u);   // RNE
    return (unsigned short)(r >> 16);
}

// ---------------------------------------------------------------------------
// Kernel 1: pack W (COUT,CIN,K) fp32 -> bf16 in MFMA A-fragment order.
// Wp[((k*4+m)*64 + lane)*8 + j] = bf16( W[o=m*16+(lane&15)][c=(lane>>4)*8+j][k] )
// ---------------------------------------------------------------------------
__global__ __launch_bounds__(256) void wpack_kernel(const float* __restrict__ W,
                                                    unsigned short* __restrict__ Wp) {
    int e = blockIdx.x * 256 + threadIdx.x;
    if (e >= 18432) return;
    int j = e & 7;
    int l = (e >> 3) & 63;
    int m = (e >> 9) & 3;
    int k = e >> 11;                       // 0..8
    int o = m * 16 + (l & 15);
    int c = ((l >> 4) << 3) + j;
    Wp[e] = f2bf(W[(o * CIN + c) * KNB + k]);
}

// ---------------------------------------------------------------------------
// Kernel 2: transpose+convert x (B,CIN,NPIX) fp32 -> xT pixel-major:
// xT[p][b][c] bf16 — 256 B per pixel. float4 NT loads (single-use x),
// LDS [64][68], REGULAR xT stores (keep xT warm in L2/L3 for conv's
// first-touch gathers). Single-lever test this round.
// ---------------------------------------------------------------------------
__global__ __launch_bounds__(256) void xpose_kernel(const float* __restrict__ x,
                                                    unsigned short* __restrict__ xT) {
    __shared__ unsigned int lds[64][68];
    int t  = threadIdx.x;
    int p0 = blockIdx.x * 64;                // 3072 blocks
    int c2 = t >> 4;                         // channel pair 0..15
    int pg = (t & 15) * 4;                   // pixel group of 4

    #pragma unroll
    for (int b = 0; b < 4; ++b) {
        const float* xr = x + ((size_t)(b * CIN + 2 * c2)) * NPIX + p0 + pg;
        f32x4 lo = __builtin_nontemporal_load((const f32x4*)xr);
        f32x4 hi = __builtin_nontemporal_load((const f32x4*)(xr + NPIX));
        #pragma unroll
        for (int j = 0; j < 4; ++j)
            lds[pg + j][b * 16 + c2] =
                (unsigned int)f2bf(lo[j]) | ((unsigned int)f2bf(hi[j]) << 16);
    }
    __syncthreads();
    unsigned int* dst = (unsigned int*)xT + (size_t)p0 * 64;
    #pragma unroll
    for (int i = 0; i < 4; ++i) {
        int ub = (i * 256 + t) * 4;          // uint index, 16B-aligned
        uint4v v = *(const uint4v*)&lds[ub >> 6][ub & 63];
        *(uint4v*)(dst + ub) = v;            // regular store (L2-resident)
    }
}

// ---------------------------------------------------------------------------
// Kernel 3: main gather + MFMA GEMM, batch-fused.
// Block = 64 pixels x ALL 4 batches; wave w handles batch w.
// __launch_bounds__(256,4): r12 proved (256,8) forces VGPR=32 -> accumulator
// spill to scratch (WRITE 197MB->1.44GB, conv 117->473us). 4 blocks/CU is
// the occupancy ceiling with 64-VGPR accumulators. unroll 3 (r9: unroll-9
// regressed). Epilogue: wave-private LDS transpose -> full-line NT stores.
// ---------------------------------------------------------------------------
template <bool TR>
__global__ __launch_bounds__(256, 4) void conv_kernel(const unsigned short* __restrict__ xT,
                                                      const float* __restrict__ x,
                                                      const int* __restrict__ nbr,
                                                      const unsigned short* __restrict__ Wp,
                                                      const float* __restrict__ bias,
                                                      float* __restrict__ out) {
    __shared__ int   ilds[576];              // 64 px * 9 nbrs
    __shared__ float elds[4][16][68];        // per-wave transpose tile, 17.4 KB

    int t  = threadIdx.x;
    int p0 = blockIdx.x * 64;                // 3072 blocks

    for (int i = t; i < 576; i += 256) {
        int idx = __builtin_nontemporal_load(&nbr[p0 * KNB + i]);
        ilds[i] = TR ? (idx << 8) : idx;     // *256B pixel block
    }
    __syncthreads();

    int lane = t & 63;
    int w    = t >> 6;                       // wave = batch
    int r    = lane & 15;
    int q    = lane >> 4;

    f32x4 acc[4][4] = {};                    // [m-tile][px-frag]

    const char* xb = (const char*)xT + w * 64 + q * 16;
    const unsigned short* wl = Wp + (size_t)lane * 8;

    int prow[4];
    #pragma unroll
    for (int f = 0; f < 4; ++f) prow[f] = (f * 16 + r) * KNB;

    #pragma unroll 3
    for (int k = 0; k < KNB; ++k) {
        short8 bfrag[4];
        #pragma unroll
        for (int f = 0; f < 4; ++f) {
            int off = ilds[prow[f] + k];
            if (TR) {
                bfrag[f] = *(const short8*)(xb + off);
            } else {
                const float* xc = x + (size_t)(w * CIN + q * 8) * NPIX + off;
                #pragma unroll
                for (int j = 0; j < 8; ++j)
                    bfrag[f][j] = (short)f2bf(xc[(size_t)j * NPIX]);
            }
        }
        short8 afr[4];
        #pragma unroll
        for (int m = 0; m < 4; ++m)
            afr[m] = *(const short8*)(wl + (((k << 2) | m) << 9));   // ((k*4+m)*64)*8
        #pragma unroll
        for (int m = 0; m < 4; ++m)
            #pragma unroll
            for (int f = 0; f < 4; ++f)
                acc[m][f] = __builtin_amdgcn_mfma_f32_16x16x32_bf16(
                                afr[m], bfrag[f], acc[m][f], 0, 0, 0);
    }

    // epilogue: per m-tile, transpose through wave-private LDS -> full-line
    // NT stores. acc[m][f][rr] = (cout_local = q*4+rr, px = f*16+r)
    float* ob = out + (size_t)w * COUT * NPIX + p0;
    #pragma unroll
    for (int m = 0; m < 4; ++m) {
        f32x4 bv = *(const f32x4*)(bias + m * 16 + q * 4);
        #pragma unroll
        for (int f = 0; f < 4; ++f)
            #pragma unroll
            for (int rr = 0; rr < 4; ++rr)
                elds[w][q * 4 + rr][f * 16 + r] = acc[m][f][rr] + bv[rr];
        #pragma unroll
        for (int i = 0; i < 4; ++i) {
            int g   = i * 64 + lane;         // 0..255 per wave
            int row = g >> 4;                // 0..15
            int col = (g & 15) * 4;          // 0..60
            f32x4 v = *(const f32x4*)&elds[w][row][col];
            __builtin_nontemporal_store(v,
                (f32x4*)(ob + (size_t)(m * 16 + row) * NPIX + col));
        }
    }
}

// ---------------------------------------------------------------------------
extern "C" void kernel_launch(void* const* d_in, const int* in_sizes, int n_in,
                              void* d_out, int out_size, void* d_ws, size_t ws_size,
                              hipStream_t stream) {
    const float* x    = (const float*)d_in[0];
    const int*   nbr  = (const int*)d_in[1];
    const float* W    = (const float*)d_in[2];
    const float* bias = (const float*)d_in[3];
    float*       out  = (float*)d_out;

    const size_t wp_bytes = 18432 * sizeof(unsigned short);           // 36,864
    const size_t wp_pad   = (wp_bytes + 255) & ~(size_t)255;
    const size_t xT_bytes = (size_t)BATCH * NPIX * CIN * 2;           // ~50.3 MB

    unsigned short* Wp = (unsigned short*)d_ws;
    unsigned short* xT = (unsigned short*)((char*)d_ws + wp_pad);

    bool full = ws_size >= wp_pad + xT_bytes;

    wpack_kernel<<<72, 256, 0, stream>>>(W, Wp);
    if (full) {
        xpose_kernel<<<NPIX / 64, 256, 0, stream>>>(x, xT);
        conv_kernel<true><<<NPIX / 64, 256, 0, stream>>>(xT, x, nbr, Wp, bias, out);
    } else {
        conv_kernel<false><<<NPIX / 64, 256, 0, stream>>>(xT, x, nbr, Wp, bias, out);
    }
}